// Round 12
// baseline (2551.556 us; speedup 1.0000x reference)
//
#include <hip/hip_runtime.h>

#define S_ 512
#define B_ 64
#define I_ 1024
#define H_ 1024
#define G_ 4096   // 4*H
#define ROWB 2080 // LDS row stride bytes: 130*16 -> conflict-free frag reads (verified R6)

typedef _Float16 f16x4 __attribute__((ext_vector_type(4)));
typedef _Float16 f16x8 __attribute__((ext_vector_type(8)));
typedef float f32x4 __attribute__((ext_vector_type(4)));

// ---------------- f32 -> f16 (plain) ----------------
__global__ __launch_bounds__(256) void cvt_f32_f16(const float* __restrict__ src,
                                                   _Float16* __restrict__ dst, int n) {
  const int stride = gridDim.x * blockDim.x * 4;
  for (long i = (long)(blockIdx.x * blockDim.x + threadIdx.x) * 4; i < n; i += stride) {
    const float4 v = *(const float4*)(src + i);
    f16x4 o;
    o.x = (_Float16)v.x;
    o.y = (_Float16)v.y;
    o.z = (_Float16)v.z;
    o.w = (_Float16)v.w;
    *(f16x4*)(dst + i) = o;
  }
}

// ---------------- async global->LDS helper (16B per lane) ----------------
__device__ __forceinline__ void gload16(const void* g, void* l) {
  __builtin_amdgcn_global_load_lds(
      (const __attribute__((address_space(1))) unsigned int*)g,
      (__attribute__((address_space(3))) unsigned int*)l, 16, 0, 0);
}

// ---------------- coherent (bypass L1/L2, served by MALL) access helpers ----------------
__device__ __forceinline__ uint4 ld_coh_x4(const unsigned int* p) {
  uint4 v;
  asm volatile("global_load_dwordx4 %0, %1, off sc0 sc1" : "=v"(v) : "v"(p) : "memory");
  return v;
}
__device__ __forceinline__ uint2 ld_coh_x2_wait(const unsigned int* p) {
  uint2 v;
  asm volatile("global_load_dwordx2 %0, %1, off sc0 sc1\n\ts_waitcnt vmcnt(0)"
               : "=&v"(v) : "v"(p) : "memory");
  return v;
}
__device__ __forceinline__ void st_coh(unsigned int* p, unsigned int v) {
  asm volatile("global_store_dword %0, %1, off sc0 sc1" : : "v"(p), "v"(v) : "memory");
}
__device__ __forceinline__ void st_coh16(unsigned short* p, unsigned int v) {
  asm volatile("global_store_short %0, %1, off sc0 sc1" : : "v"(p), "v"(v) : "memory");
}
__device__ __forceinline__ void wait_vm0() {
  asm volatile("s_waitcnt vmcnt(0)" ::: "memory");
}
// self-contained (waitcnt inside) -> spill-safe even at high VGPR pressure (R9 lesson)
__device__ __forceinline__ f16x8 ld_g_f16x8_wait(const _Float16* p) {
  f16x8 v;
  asm volatile("global_load_dwordx4 %0, %1, off\n\ts_waitcnt vmcnt(0)"
               : "=&v"(v) : "v"(p) : "memory");
  return v;
}

// ---------------- x_gates GEMM: C = f16(x) * f16(Wx)^T + (bx+bh), f16 out ----------------
// (verified R10/R11) m97 structure, single product. 128x128 tile, BK=32, 4 waves.
__global__ __launch_bounds__(256) void gemm_xg(const _Float16* __restrict__ A,
                                               const _Float16* __restrict__ Bm,
                                               const float* __restrict__ bx,
                                               const float* __restrict__ bh,
                                               _Float16* __restrict__ C) {
  __shared__ __align__(16) _Float16 As[128 * 32];
  __shared__ __align__(16) _Float16 Bs[128 * 32];
  const int tileN = (blockIdx.x & 31) << 7;
  const int tileM = (blockIdx.x >> 5) << 7;
  const int w = threadIdx.x >> 6;
  const int lane = threadIdx.x & 63;
  const int wm = w & 1, wn = w >> 1;

  const int srow = lane >> 2;
  const int scol = (lane & 3) << 3;
  const long r0 = (long)((2 * w + 0) * 16 + srow);
  const long r1 = (long)((2 * w + 1) * 16 + srow);
  const _Float16* pA0 = A + (tileM + r0) * I_ + scol;
  const _Float16* pA1 = A + (tileM + r1) * I_ + scol;
  const _Float16* pB0 = Bm + (tileN + r0) * I_ + scol;
  const _Float16* pB1 = Bm + (tileN + r1) * I_ + scol;

  f32x4 acc[4][4] = {};
  const int fr = lane & 15;
  const int fk = (lane >> 4) << 3;

  for (int kk = 0; kk < I_; kk += 32) {
    gload16(pA0 + kk, &As[(2 * w + 0) * 512]);
    gload16(pA1 + kk, &As[(2 * w + 1) * 512]);
    gload16(pB0 + kk, &Bs[(2 * w + 0) * 512]);
    gload16(pB1 + kk, &Bs[(2 * w + 1) * 512]);
    __syncthreads();
    f16x8 af[4], bf[4];
#pragma unroll
    for (int i = 0; i < 4; ++i) {
      af[i] = *(const f16x8*)&As[(wm * 64 + i * 16 + fr) * 32 + fk];
      bf[i] = *(const f16x8*)&Bs[(wn * 64 + i * 16 + fr) * 32 + fk];
    }
#pragma unroll
    for (int i = 0; i < 4; ++i)
#pragma unroll
      for (int j = 0; j < 4; ++j)
        acc[i][j] = __builtin_amdgcn_mfma_f32_16x16x32_f16(af[i], bf[j], acc[i][j], 0, 0, 0);
    __syncthreads();
  }

#pragma unroll
  for (int j = 0; j < 4; ++j) {
    const int col = tileN + wn * 64 + j * 16 + fr;
    const float bias = bx[col] + bh[col];
#pragma unroll
    for (int i = 0; i < 4; ++i) {
      const int row0 = tileM + wm * 64 + i * 16 + ((lane >> 4) << 2);
#pragma unroll
      for (int r = 0; r < 4; ++r)
        C[(long)(row0 + r) * G_ + col] = (_Float16)(acc[i][j][r] + bias);
    }
  }
}

// ---------------- flag reset (every launch, stream-ordered) ----------------
__global__ void zero_counters(unsigned int* c, int n) {
  for (int i = threadIdx.x; i < n; i += blockDim.x) c[i] = 0;
}

// ---------------- persistent LSTM scan: 128 WGs, cohort = 32 ----------------
// WG = (bg 0..3, hs 0..31): 16 batches x 32 hidden. Wave w = gate w, output
// 16x32 via 2 N-tiles; Wh fully in 256 VGPRs/lane (64 frags, self-contained
// loads). Each wave polls ALL 128 cohort flags itself (dwordx2/lane) -> no
// post-poll barrier. 2 barriers/step order hhS and gbuf reuse:
//   stage(t) -> BAR1 -> MFMA reads hhS(t) + gbuf write -> BAR2 -> gbuf read
//   -> cell/publish/poll -> stage(t+1)   [hhS(t+1) writes are post-BAR2(t);
//   gbuf(t+1) writes are post-BAR1(t+1), after every wave's gbuf read(t)].
__global__ __launch_bounds__(256, 1) void lstm_scan(
    const _Float16* __restrict__ xg, const _Float16* __restrict__ Whh,
    unsigned short* __restrict__ hH0, unsigned short* __restrict__ hH1,
    float* __restrict__ out, float* __restrict__ hT, float* __restrict__ cT,
    unsigned int* __restrict__ flags) {
  __shared__ __align__(16) char hhS[16 * ROWB];  // 33.3 KB
  __shared__ float gbuf[4][16][32];              // 8 KB
  const int bg = blockIdx.x >> 5;
  const int hs = blockIdx.x & 31;
  const int tid = threadIdx.x;
  const int w = tid >> 6;
  const int lane = tid & 63;
  const int fr = lane & 15;
  const int fkg = lane >> 4;  // 0..3

  // ---- Wh -> regs, once: gate w, hidden rows hs*32..+32 (2 N-tiles) ----
  f16x8 wreg0[32], wreg1[32];  // 256 VGPRs
  {
    const _Float16* w0 = Whh + (long)(w * H_ + hs * 32 + fr) * H_ + fkg * 8;
    const _Float16* w1 = Whh + (long)(w * H_ + hs * 32 + 16 + fr) * H_ + fkg * 8;
#pragma unroll
    for (int kt = 0; kt < 32; ++kt) {
      wreg0[kt] = ld_g_f16x8_wait(w0 + kt * 32);
      wreg1[kt] = ld_g_f16x8_wait(w1 + kt * 32);
    }
  }

  const int b = tid >> 4, j = tid & 15;
  const int gb = bg * 16 + b;
  const int gj0 = hs * 32 + j;   // this thread's 2 hidden units
  const int gj1 = gj0 + 16;
  float c0v = 0.f, c1v = 0.f;

  // staging source (u32 units): plane f16[64][1024]; bg block = 8192 u32 (32KB)
  const unsigned int* sP0 = (const unsigned int*)hH0 + bg * 8192 + tid * 4;
  const unsigned int* sP1 = (const unsigned int*)hH1 + bg * 8192 + tid * 4;
  const int lds0 = (tid >> 7) * ROWB + (tid & 127) * 16;
  const char* hhrow = hhS + fr * ROWB + fkg * 16;
  // cohort flags: words [bg*128, bg*128+128); lane covers 2 via dwordx2
  const unsigned int* pollp = flags + bg * 128 + 2 * lane;
  unsigned int* myflag = flags + blockIdx.x * 4 + w;

  // xg prefetch for t=0
  float gi0, gf0, gg0, go0, gi1, gf1, gg1, go1;
  {
    const _Float16* xq = xg + (long)gb * G_;
    gi0 = (float)xq[gj0];           gi1 = (float)xq[gj1];
    gf0 = (float)xq[H_ + gj0];      gf1 = (float)xq[H_ + gj1];
    gg0 = (float)xq[2 * H_ + gj0];  gg1 = (float)xq[2 * H_ + gj1];
    go0 = (float)xq[3 * H_ + gj0];  go1 = (float)xq[3 * H_ + gj1];
  }

  for (int t = 0; t < S_; ++t) {
    if (t > 0) {
      // ---- every wave polls all 32 cohort WGs x 4 wave-flags ----
      const unsigned tgt = (unsigned)t;
      for (;;) {
        const uint2 f = ld_coh_x2_wait(pollp);
        if (__all(f.x >= tgt && f.y >= tgt)) break;
        __builtin_amdgcn_s_sleep(1);
      }

      // ---- stage h(t-1) plane -> LDS (32KB, 8 dwordx4/thread) ----
      const unsigned int* sP = (t & 1) ? sP0 : sP1;
      uint4 qh[8];
#pragma unroll
      for (int i = 0; i < 8; ++i) qh[i] = ld_coh_x4(sP + i * 1024);
      wait_vm0();
      __builtin_amdgcn_sched_barrier(0);
#pragma unroll
      for (int i = 0; i < 8; ++i)
        *(uint4*)(hhS + lds0 + i * (2 * ROWB)) = qh[i];
      __syncthreads();  // BAR1

      // ---- gates = h @ Wh^T : 2 N-tiles x 32 k-frags, 4 chains ----
      f32x4 a0 = {}, a1 = {}, a2 = {}, a3 = {};
#pragma unroll
      for (int kt = 0; kt < 32; kt += 2) {
        const f16x8 h0 = *(const f16x8*)(hhrow + kt * 64);
        const f16x8 h1 = *(const f16x8*)(hhrow + (kt + 1) * 64);
        a0 = __builtin_amdgcn_mfma_f32_16x16x32_f16(h0, wreg0[kt], a0, 0, 0, 0);
        a1 = __builtin_amdgcn_mfma_f32_16x16x32_f16(h1, wreg0[kt + 1], a1, 0, 0, 0);
        a2 = __builtin_amdgcn_mfma_f32_16x16x32_f16(h0, wreg1[kt], a2, 0, 0, 0);
        a3 = __builtin_amdgcn_mfma_f32_16x16x32_f16(h1, wreg1[kt + 1], a3, 0, 0, 0);
      }
#pragma unroll
      for (int r = 0; r < 4; ++r) {
        gbuf[w][fkg * 4 + r][fr] = a0[r] + a1[r];
        gbuf[w][fkg * 4 + r][16 + fr] = a2[r] + a3[r];
      }
      __syncthreads();  // BAR2
      gi0 += gbuf[0][b][j];      gi1 += gbuf[0][b][j + 16];
      gf0 += gbuf[1][b][j];      gf1 += gbuf[1][b][j + 16];
      gg0 += gbuf[2][b][j];      gg1 += gbuf[2][b][j + 16];
      go0 += gbuf[3][b][j];      go1 += gbuf[3][b][j + 16];
    }

    const float i0 = 1.f / (1.f + __expf(-gi0));
    const float f0 = 1.f / (1.f + __expf(-gf0));
    const float z0 = tanhf(gg0);
    const float o0 = 1.f / (1.f + __expf(-go0));
    c0v = f0 * c0v + i0 * z0;
    const float hn0 = o0 * tanhf(c0v);

    const float i1 = 1.f / (1.f + __expf(-gi1));
    const float f1 = 1.f / (1.f + __expf(-gf1));
    const float z1 = tanhf(gg1);
    const float o1 = 1.f / (1.f + __expf(-go1));
    c1v = f1 * c1v + i1 * z1;
    const float hn1 = o1 * tanhf(c1v);

    if (t + 1 < S_) {
      // ---- publish h(t) to parity plane (2 values), wave-drain, wave flag ----
      unsigned short* base = ((t & 1) ? hH1 : hH0) + gb * 1024;
      st_coh16(base + gj0, (unsigned)__builtin_bit_cast(unsigned short, (_Float16)hn0));
      st_coh16(base + gj1, (unsigned)__builtin_bit_cast(unsigned short, (_Float16)hn1));
      wait_vm0();  // this wave's h stores visible at the coherent point
      if (lane == 0) st_coh(myflag, (unsigned)(t + 1));
      // off-critical-path work after the flag
      float* op = out + ((long)gb * S_ + t) * H_;
      op[gj0] = hn0;
      op[gj1] = hn1;
      const _Float16* xq = xg + ((long)(t + 1) * B_ + gb) * G_;
      gi0 = (float)xq[gj0];           gi1 = (float)xq[gj1];
      gf0 = (float)xq[H_ + gj0];      gf1 = (float)xq[H_ + gj1];
      gg0 = (float)xq[2 * H_ + gj0];  gg1 = (float)xq[2 * H_ + gj1];
      go0 = (float)xq[3 * H_ + gj0];  go1 = (float)xq[3 * H_ + gj1];
    } else {
      float* op = out + ((long)gb * S_ + t) * H_;
      op[gj0] = hn0;
      op[gj1] = hn1;
      hT[gb * H_ + gj0] = hn0;
      hT[gb * H_ + gj1] = hn1;
      cT[gb * H_ + gj0] = c0v;
      cT[gb * H_ + gj1] = c1v;
    }
  }
}

// ---------------- launch ----------------
extern "C" void kernel_launch(void* const* d_in, const int* in_sizes, int n_in,
                              void* d_out, int out_size, void* d_ws, size_t ws_size,
                              hipStream_t stream) {
  const float* x = (const float*)d_in[0];
  const float* Wx = (const float*)d_in[1];
  const float* bx = (const float*)d_in[2];
  const float* Wh = (const float*)d_in[3];
  const float* bh = (const float*)d_in[4];

  float* out = (float*)d_out;            // [64][512][1024]
  float* hT = out + (long)B_ * S_ * H_;  // [64][1024]
  float* cT = hT + (long)B_ * H_;        // [64][1024]

  char* ws = (char*)d_ws;
  _Float16* Wx16 = (_Float16*)ws;                  // 8 MB
  _Float16* Whh = (_Float16*)(ws + (8l << 20));    // 8 MB
  _Float16* x16 = (_Float16*)(ws + (16l << 20));   // 64 MB
  char* st = ws + (80l << 20);
  unsigned short* hH0 = (unsigned short*)(st);                 // 128 KB
  unsigned short* hH1 = (unsigned short*)(st + (128l << 10));  // 128 KB
  unsigned int* flags = (unsigned int*)(st + (256l << 10));    // 2 KB (512 flags)
  _Float16* xg = (_Float16*)(ws + (96l << 20));    // 256 MB -> total 352 MB

  cvt_f32_f16<<<256, 256, 0, stream>>>(Wx, Wx16, G_ * I_);
  cvt_f32_f16<<<256, 256, 0, stream>>>(Wh, Whh, G_ * H_);
  cvt_f32_f16<<<2048, 256, 0, stream>>>(x, x16, S_ * B_ * I_);
  zero_counters<<<1, 256, 0, stream>>>(flags, 512);

  const int nGemmBlk = (S_ * B_ / 128) * (G_ / 128);
  gemm_xg<<<nGemmBlk, 256, 0, stream>>>(x16, Wx16, bx, bh, xg);

  lstm_scan<<<128, 256, 0, stream>>>(xg, Whh, hH0, hH1, out, hT, cT, flags);
}